// Round 5
// baseline (232.430 us; speedup 1.0000x reference)
//
#include <hip/hip_runtime.h>
#include <hip/hip_bf16.h>
#include <math.h>

#define HID 128
#define NH 8
#define DH 16

typedef __bf16 bf16x8 __attribute__((ext_vector_type(8)));
typedef float  f32x4  __attribute__((ext_vector_type(4)));

// ---------------------------------------------------------------------------
// Kernel 1 (prep): fused rowptr binary-search + W hi/lo split + bias384.
// ---------------------------------------------------------------------------
__global__ void prep_kernel(const int* __restrict__ row, int* __restrict__ row_ptr,
                            int N_, int E_,
                            const float* __restrict__ Wq, const float* __restrict__ Wk,
                            const float* __restrict__ Wv, const float* __restrict__ Wo,
                            const float* __restrict__ bq, const float* __restrict__ bk,
                            const float* __restrict__ bv,
                            __bf16* __restrict__ Whi, __bf16* __restrict__ Wlo,
                            float* __restrict__ bias384) {
    int idx = blockIdx.x * blockDim.x + threadIdx.x;
    if (idx < 4 * 16384) {
        int j = idx >> 14;
        int rem = idx & 16383;
        const float* W = (j == 0) ? Wq : (j == 1) ? Wk : (j == 2) ? Wv : Wo;
        float x = W[rem];
        __bf16 hv = (__bf16)x;
        Whi[idx] = hv;
        Wlo[idx] = (__bf16)(x - (float)hv);
    }
    if (idx <= N_) {
        int lo = 0, hi = E_;
        while (lo < hi) {
            int mid = (lo + hi) >> 1;
            if (row[mid] < idx) lo = mid + 1; else hi = mid;
        }
        row_ptr[idx] = lo;
    }
    if (idx < 384) {
        int j = idx >> 7;
        int pcol = idx & 127;                       // head-major col within proj
        int o = ((pcol & 15) << 3) | (pcol >> 4);   // original W row
        const float* b = (j == 0) ? bq : (j == 1) ? bk : bv;
        bias384[idx] = b[o];
    }
}

// ---------------------------------------------------------------------------
// Kernel 2: fused QKV projection via MFMA (bf16 hi/lo split = fp32 accuracy).
// 32-row M-tiles (grid ~1563 -> ~16 waves/CU resident) for latency hiding.
// A-tile staged in LDS, coalesced + XOR bank-swizzle.  Per k-step: issue all
// 12 W-fragment loads FIRST, then A hi/lo split VALU (hides W L2 latency),
// then the MFMA cluster.  q stored fp32 [N][128] head-major; k,v bf16
// interleaved kv[N][256] via LDS transpose -> coalesced uint4 stores.
// ---------------------------------------------------------------------------
__global__ __launch_bounds__(256)
void qkv_mfma_kernel(const float* __restrict__ h, int M,
                     const __bf16* __restrict__ Whi, const __bf16* __restrict__ Wlo,
                     const float* __restrict__ bias384,
                     float* __restrict__ q, __bf16* __restrict__ kv) {
    __shared__ float As[32 * 128];          // 16 KB; reused as bf16 kv buffer
    int tid  = threadIdx.x;
    int wv   = tid >> 6;
    int lane = tid & 63;
    int r    = lane & 15;
    int kg   = lane >> 4;
    int m0   = blockIdx.x * 32;
    int colbase = wv * 96;

    // ---- stage A tile (32 x 128 f32), coalesced, swizzled ----
    #pragma unroll
    for (int it = 0; it < 4; ++it) {
        int flat = it * 256 + tid;          // float4 slot 0..1023
        int row  = flat >> 5;               // 0..31
        int s    = flat & 31;               // LDS col4 slot
        int g    = s ^ (row & 7);           // global col4 (involution)
        int grow = m0 + row; if (grow > M - 1) grow = M - 1;
        *(float4*)&As[row * 128 + s * 4] =
            *(const float4*)&h[(size_t)grow * 128 + g * 4];
    }
    __syncthreads();

    f32x4 acc[6][2];
    #pragma unroll
    for (int cf = 0; cf < 6; ++cf)
        #pragma unroll
        for (int rf = 0; rf < 2; ++rf)
            acc[cf][rf] = (f32x4){0.f, 0.f, 0.f, 0.f};

    int wrow[6];
    #pragma unroll
    for (int cf = 0; cf < 6; ++cf) {
        int col  = colbase + cf * 16 + r;
        int j    = col >> 7;
        int pcol = col & 127;
        int o    = ((pcol & 15) << 3) | (pcol >> 4);
        wrow[cf] = (j * 128 + o) * 128;
    }

    #pragma unroll
    for (int t = 0; t < 4; ++t) {
        int k0 = t * 32 + kg * 8;
        int c0 = k0 >> 2;                   // even col4 index
        // issue W loads first (L2-resident; latency hidden by A-split below)
        bf16x8 bh[6], bl[6];
        #pragma unroll
        for (int cf = 0; cf < 6; ++cf) {
            bh[cf] = *(const bf16x8*)&Whi[wrow[cf] + k0];
            bl[cf] = *(const bf16x8*)&Wlo[wrow[cf] + k0];
        }
        // A fragments from LDS + hi/lo split (VALU)
        bf16x8 Ahi[2], Alo[2];
        #pragma unroll
        for (int rf = 0; rf < 2; ++rf) {
            int row = rf * 16 + r;
            int sw  = r & 7;
            float4 xa = *(float4*)&As[row * 128 + ((c0    ) ^ sw) * 4];
            float4 xb = *(float4*)&As[row * 128 + ((c0 + 1) ^ sw) * 4];
            float xs[8] = {xa.x, xa.y, xa.z, xa.w, xb.x, xb.y, xb.z, xb.w};
            #pragma unroll
            for (int e = 0; e < 8; ++e) {
                __bf16 hv = (__bf16)xs[e];
                Ahi[rf][e] = hv;
                Alo[rf][e] = (__bf16)(xs[e] - (float)hv);
            }
        }
        // MFMA cluster
        #pragma unroll
        for (int cf = 0; cf < 6; ++cf) {
            #pragma unroll
            for (int rf = 0; rf < 2; ++rf) {
                acc[cf][rf] = __builtin_amdgcn_mfma_f32_16x16x32_bf16(Ahi[rf], bh[cf], acc[cf][rf], 0, 0, 0);
                acc[cf][rf] = __builtin_amdgcn_mfma_f32_16x16x32_bf16(Alo[rf], bh[cf], acc[cf][rf], 0, 0, 0);
                acc[cf][rf] = __builtin_amdgcn_mfma_f32_16x16x32_bf16(Ahi[rf], bl[cf], acc[cf][rf], 0, 0, 0);
            }
        }
    }

    // ---- epilogue: q direct; kv through LDS for coalesced stores ----
    __syncthreads();                        // all As reads done; reuse buffer
    __bf16* kvs = (__bf16*)As;              // 32 x 256 bf16 = 16 KB
    int orow = kg * 4;
    #pragma unroll
    for (int cf = 0; cf < 6; ++cf) {
        int col  = colbase + cf * 16 + r;
        int j    = col >> 7;                // 0=q 1=k 2=v (uniform per cf)
        int pcol = col & 127;
        float b  = bias384[col];
        #pragma unroll
        for (int rf = 0; rf < 2; ++rf) {
            #pragma unroll
            for (int e = 0; e < 4; ++e) {
                int mrow = rf * 16 + orow + e;      // 0..31
                float val = acc[cf][rf][e] + b;
                if (j == 0) {
                    int mg = m0 + mrow;
                    if (mg < M) q[(size_t)mg * 128 + pcol] = val;
                } else {
                    int gi  = pcol >> 2;
                    int idx = gi * 8 + ((j == 1) ? 0 : 4) + (pcol & 3);
                    kvs[mrow * 256 + idx] = (__bf16)val;
                }
            }
        }
    }
    __syncthreads();
    #pragma unroll
    for (int it = 0; it < 4; ++it) {
        int flat = it * 256 + tid;          // 16B chunk 0..1023
        int row  = flat >> 5;
        int c    = flat & 31;
        int mg   = m0 + row;
        if (mg < M)
            *(uint4*)&kv[(size_t)mg * 256 + c * 8] = *(uint4*)&kvs[row * 256 + c * 8];
    }
}

// ---------------------------------------------------------------------------
// Kernel 3: fused SDDMM + online segment-softmax + SPMM.
// One wave per node; halves (32+32) each process 2 edges per main-loop iter.
// Lane sl owns head-major channels 4sl..4sl+3; one dwordx4 per edge delivers
// k4|v4 (bf16).  Output in reference layout.
// ---------------------------------------------------------------------------
__device__ __forceinline__ float blo(unsigned u) { return __uint_as_float(u << 16); }
__device__ __forceinline__ float bhi(unsigned u) { return __uint_as_float(u & 0xffff0000u); }

__global__ __launch_bounds__(256)
void edge_attn_kernel(const int* __restrict__ row_ptr, const int* __restrict__ col,
                      const float* __restrict__ q, const __bf16* __restrict__ kv,
                      float* __restrict__ out, int N_) {
    int wave = threadIdx.x >> 6;
    int lane = threadIdx.x & 63;
    int node = blockIdx.x * 4 + wave;
    if (node >= N_) return;
    int sl   = lane & 31;
    int half = lane >> 5;

    float4 q4 = *(const float4*)&q[(size_t)node * 128 + sl * 4];
    int e0 = row_ptr[node];
    int e1 = row_ptr[node + 1];

    float m = -INFINITY, z = 0.f;
    float4 acc = make_float4(0.f, 0.f, 0.f, 0.f);

    auto score = [&](uint4 u) {
        float p = q4.x * blo(u.x) + q4.y * bhi(u.x) +
                  q4.z * blo(u.y) + q4.w * bhi(u.y);
        p += __shfl_xor(p, 1);
        p += __shfl_xor(p, 2);
        return p * 0.25f;                       // 1/sqrt(DH)
    };
    auto update = [&](float s, uint4 u) {
        float mnew  = fmaxf(m, s);
        float alpha = __expf(m - mnew);
        float w     = __expf(s - mnew);
        z = z * alpha + w;
        acc.x = acc.x * alpha + w * blo(u.z);
        acc.y = acc.y * alpha + w * bhi(u.z);
        acc.z = acc.z * alpha + w * blo(u.w);
        acc.w = acc.w * alpha + w * bhi(u.w);
        m = mnew;
    };

    int eb = e0;
    for (; eb + 4 <= e1; eb += 4) {
        int ea = eb + half * 2;
        int c0 = col[ea];
        int c1 = col[ea + 1];
        uint4 u0 = *(const uint4*)(kv + (size_t)c0 * 256 + sl * 8);
        uint4 u1 = *(const uint4*)(kv + (size_t)c1 * 256 + sl * 8);
        float s0 = score(u0);
        float s1 = score(u1);
        update(s0, u0);
        update(s1, u1);
    }
    for (; eb < e1; eb += 2) {
        int my_e   = eb + half;
        bool valid = (my_e < e1);
        int cnode  = valid ? col[my_e] : col[eb];
        uint4 u = *(const uint4*)(kv + (size_t)cnode * 256 + sl * 8);
        float s = valid ? score(u) : -INFINITY;
        float mnew = fmaxf(m, s);
        if (mnew > -INFINITY) {
            float alpha = __expf(m - mnew);
            float w     = __expf(s - mnew);
            z = z * alpha + w;
            acc.x = acc.x * alpha + w * blo(u.z);
            acc.y = acc.y * alpha + w * bhi(u.z);
            acc.z = acc.z * alpha + w * blo(u.w);
            acc.w = acc.w * alpha + w * bhi(u.w);
            m = mnew;
        }
    }

    float m2 = __shfl_xor(m, 32);
    float z2 = __shfl_xor(z, 32);
    float ax = __shfl_xor(acc.x, 32);
    float ay = __shfl_xor(acc.y, 32);
    float az = __shfl_xor(acc.z, 32);
    float aw = __shfl_xor(acc.w, 32);
    float mm = fmaxf(m, m2);
    if (mm > -INFINITY) {
        float a1 = __expf(m - mm);
        float a2 = __expf(m2 - mm);
        z = z * a1 + z2 * a2;
        acc.x = acc.x * a1 + ax * a2;
        acc.y = acc.y * a1 + ay * a2;
        acc.z = acc.z * a1 + az * a2;
        acc.w = acc.w * a1 + aw * a2;
    }

    if (half == 0) {
        float inv = (z > 0.f) ? 1.0f / z : 0.f;
        float rr[4] = {acc.x * inv, acc.y * inv, acc.z * inv, acc.w * inv};
        #pragma unroll
        for (int jj = 0; jj < 4; ++jj) {
            int cp = sl * 4 + jj;
            int d  = cp & 15;
            int hd = cp >> 4;
            out[(size_t)node * HID + d * 8 + hd] = rr[jj];
        }
    }
}

// ---------------------------------------------------------------------------
// Kernel 4: output projection via MFMA hi/lo split, 32-row tiles, LDS-staged
// A, W loads issued before the A-split VALU (same schedule as kernel 2).
// ---------------------------------------------------------------------------
__global__ __launch_bounds__(256)
void outproj_mfma_kernel(const float* __restrict__ A, int M,
                         const __bf16* __restrict__ Whi, const __bf16* __restrict__ Wlo,
                         const float* __restrict__ bo, float* __restrict__ C) {
    __shared__ float As[32 * 128];
    int tid  = threadIdx.x;
    int wv   = tid >> 6;
    int lane = tid & 63;
    int r    = lane & 15;
    int kg   = lane >> 4;
    int m0   = blockIdx.x * 32;
    int colbase = wv * 32;

    #pragma unroll
    for (int it = 0; it < 4; ++it) {
        int flat = it * 256 + tid;
        int row  = flat >> 5;
        int s    = flat & 31;
        int g    = s ^ (row & 7);
        int grow = m0 + row; if (grow > M - 1) grow = M - 1;
        *(float4*)&As[row * 128 + s * 4] =
            *(const float4*)&A[(size_t)grow * 128 + g * 4];
    }
    __syncthreads();

    f32x4 acc[2][2];
    #pragma unroll
    for (int cf = 0; cf < 2; ++cf)
        #pragma unroll
        for (int rf = 0; rf < 2; ++rf)
            acc[cf][rf] = (f32x4){0.f, 0.f, 0.f, 0.f};

    #pragma unroll
    for (int t = 0; t < 4; ++t) {
        int k0 = t * 32 + kg * 8;
        int c0 = k0 >> 2;
        bf16x8 bh[2], bl[2];
        #pragma unroll
        for (int cf = 0; cf < 2; ++cf) {
            int wrow = (colbase + cf * 16 + r) * 128;
            bh[cf] = *(const bf16x8*)&Whi[wrow + k0];
            bl[cf] = *(const bf16x8*)&Wlo[wrow + k0];
        }
        bf16x8 Ahi[2], Alo[2];
        #pragma unroll
        for (int rf = 0; rf < 2; ++rf) {
            int row = rf * 16 + r;
            int sw  = r & 7;
            float4 xa = *(float4*)&As[row * 128 + ((c0    ) ^ sw) * 4];
            float4 xb = *(float4*)&As[row * 128 + ((c0 + 1) ^ sw) * 4];
            float xs[8] = {xa.x, xa.y, xa.z, xa.w, xb.x, xb.y, xb.z, xb.w};
            #pragma unroll
            for (int e = 0; e < 8; ++e) {
                __bf16 hv = (__bf16)xs[e];
                Ahi[rf][e] = hv;
                Alo[rf][e] = (__bf16)(xs[e] - (float)hv);
            }
        }
        #pragma unroll
        for (int cf = 0; cf < 2; ++cf) {
            #pragma unroll
            for (int rf = 0; rf < 2; ++rf) {
                acc[cf][rf] = __builtin_amdgcn_mfma_f32_16x16x32_bf16(Ahi[rf], bh[cf], acc[cf][rf], 0, 0, 0);
                acc[cf][rf] = __builtin_amdgcn_mfma_f32_16x16x32_bf16(Alo[rf], bh[cf], acc[cf][rf], 0, 0, 0);
                acc[cf][rf] = __builtin_amdgcn_mfma_f32_16x16x32_bf16(Ahi[rf], bl[cf], acc[cf][rf], 0, 0, 0);
            }
        }
    }

    int orow = kg * 4;
    #pragma unroll
    for (int cf = 0; cf < 2; ++cf) {
        int col = colbase + cf * 16 + r;
        float b = bo[col];
        #pragma unroll
        for (int rf = 0; rf < 2; ++rf) {
            #pragma unroll
            for (int e = 0; e < 4; ++e) {
                int mg = m0 + rf * 16 + orow + e;
                if (mg < M) C[(size_t)mg * HID + col] = acc[cf][rf][e] + b;
            }
        }
    }
}

// ---------------------------------------------------------------------------
extern "C" void kernel_launch(void* const* d_in, const int* in_sizes, int n_in,
                              void* d_out, int out_size, void* d_ws, size_t ws_size,
                              hipStream_t stream) {
    const float* h  = (const float*)d_in[0];
    const int* row  = (const int*)d_in[1];
    const int* col  = (const int*)d_in[2];
    const float* Wq = (const float*)d_in[3];
    const float* bq = (const float*)d_in[4];
    const float* Wk = (const float*)d_in[5];
    const float* bk = (const float*)d_in[6];
    const float* Wv = (const float*)d_in[7];
    const float* bv = (const float*)d_in[8];
    const float* Wo = (const float*)d_in[9];
    const float* bo = (const float*)d_in[10];
    float* out = (float*)d_out;

    int N_ = in_sizes[0] / HID;   // 50000
    int E_ = in_sizes[1];         // 800000

    char* ws = (char*)d_ws;
    size_t off = 0;
    auto alloc = [&](size_t bytes) {
        void* p = (void*)(ws + off);
        off = (off + bytes + 255) & ~(size_t)255;
        return p;
    };
    int*    row_ptr = (int*)   alloc((size_t)(N_ + 1) * sizeof(int));
    float*  qb      = (float*) alloc((size_t)N_ * 128 * sizeof(float));
    __bf16* kvb     = (__bf16*)alloc((size_t)N_ * 256 * sizeof(__bf16));
    float*  ob      = (float*) alloc((size_t)N_ * HID * sizeof(float));
    __bf16* Whi     = (__bf16*)alloc((size_t)4 * 16384 * sizeof(__bf16));
    __bf16* Wlo     = (__bf16*)alloc((size_t)4 * 16384 * sizeof(__bf16));
    float*  bias384 = (float*) alloc(384 * sizeof(float));
    (void)ws_size;

    prep_kernel<<<256, 256, 0, stream>>>(row, row_ptr, N_, E_,
                                         Wq, Wk, Wv, Wo, bq, bk, bv,
                                         Whi, Wlo, bias384);
    qkv_mfma_kernel<<<(N_ + 31) / 32, 256, 0, stream>>>(h, N_, Whi, Wlo, bias384, qb, kvb);
    edge_attn_kernel<<<(N_ + 3) / 4, 256, 0, stream>>>(row_ptr, col, qb, kvb, ob, N_);
    outproj_mfma_kernel<<<(N_ + 31) / 32, 256, 0, stream>>>(
        ob, N_, Whi + 3 * 16384, Wlo + 3 * 16384, bo, out);
}

// Round 6
// 216.653 us; speedup vs baseline: 1.0728x; 1.0728x over previous
//
#include <hip/hip_runtime.h>
#include <hip/hip_bf16.h>
#include <math.h>

#define HID 128
#define NH 8
#define DH 16

typedef __bf16 bf16x8 __attribute__((ext_vector_type(8)));
typedef float  f32x4  __attribute__((ext_vector_type(4)));

// ---------------------------------------------------------------------------
// Kernel 1 (prep): fused rowptr binary-search + W hi/lo split + bias384.
// ---------------------------------------------------------------------------
__global__ void prep_kernel(const int* __restrict__ row, int* __restrict__ row_ptr,
                            int N_, int E_,
                            const float* __restrict__ Wq, const float* __restrict__ Wk,
                            const float* __restrict__ Wv, const float* __restrict__ Wo,
                            const float* __restrict__ bq, const float* __restrict__ bk,
                            const float* __restrict__ bv,
                            __bf16* __restrict__ Whi, __bf16* __restrict__ Wlo,
                            float* __restrict__ bias384) {
    int idx = blockIdx.x * blockDim.x + threadIdx.x;
    if (idx < 4 * 16384) {
        int j = idx >> 14;
        int rem = idx & 16383;
        const float* W = (j == 0) ? Wq : (j == 1) ? Wk : (j == 2) ? Wv : Wo;
        float x = W[rem];
        __bf16 hv = (__bf16)x;
        Whi[idx] = hv;
        Wlo[idx] = (__bf16)(x - (float)hv);
    }
    if (idx <= N_) {
        int lo = 0, hi = E_;
        while (lo < hi) {
            int mid = (lo + hi) >> 1;
            if (row[mid] < idx) lo = mid + 1; else hi = mid;
        }
        row_ptr[idx] = lo;
    }
    if (idx < 384) {
        int j = idx >> 7;
        int pcol = idx & 127;                       // head-major col within proj
        int o = ((pcol & 15) << 3) | (pcol >> 4);   // original W row
        const float* b = (j == 0) ? bq : (j == 1) ? bk : bv;
        bias384[idx] = b[o];
    }
}

// ---------------------------------------------------------------------------
// Kernel 2: fused QKV projection via MFMA (bf16 hi/lo split = fp32 accuracy).
// 64-row M-tile, 4 waves x 96 fused cols.  A is split fp32 -> bf16 hi/lo at
// STAGING time (conversion overlaps stage latency); LDS holds bf16 hi+lo
// with 16B-slot XOR swizzle (conflict-free ds_write_b128 / ds_read_b128).
// k-loop: 12 W loads issued first, 8 A ds_reads, then a 72-MFMA cluster --
// cluster of step t hides W-load latency of step t+1 across resident waves.
// q stored fp32 [N][128] head-major; k,v bf16 interleaved kv[N][256] via
// LDS transpose -> coalesced uint4 stores.
// ---------------------------------------------------------------------------
__global__ __launch_bounds__(256)
void qkv_mfma_kernel(const float* __restrict__ h, int M,
                     const __bf16* __restrict__ Whi, const __bf16* __restrict__ Wlo,
                     const float* __restrict__ bias384,
                     float* __restrict__ q, __bf16* __restrict__ kv) {
    __shared__ __bf16 As2[2][64 * 128];     // [0]=hi, [1]=lo; 32 KB total
    int tid  = threadIdx.x;
    int wv   = tid >> 6;
    int lane = tid & 63;
    int r    = lane & 15;
    int kg   = lane >> 4;
    int m0   = blockIdx.x * 64;
    int colbase = wv * 96;

    // ---- stage A tile: coalesced 32B reads, split to hi/lo, swizzled LDS ----
    #pragma unroll
    for (int it = 0; it < 4; ++it) {
        int flat = it * 256 + tid;          // 16B-slot task 0..1023
        int row  = flat >> 4;               // 0..63
        int s    = flat & 15;               // LDS slot (8 bf16 = 16 B)
        int g    = s ^ (row & 7);           // global slot (involution)
        int grow = m0 + row; if (grow > M - 1) grow = M - 1;
        const float* src = &h[(size_t)grow * 128 + g * 8];
        float4 x0 = *(const float4*)src;
        float4 x1 = *(const float4*)(src + 4);
        float xs[8] = {x0.x, x0.y, x0.z, x0.w, x1.x, x1.y, x1.z, x1.w};
        bf16x8 hv8, lv8;
        #pragma unroll
        for (int e = 0; e < 8; ++e) {
            __bf16 hv = (__bf16)xs[e];
            hv8[e] = hv;
            lv8[e] = (__bf16)(xs[e] - (float)hv);
        }
        *(bf16x8*)&As2[0][row * 128 + s * 8] = hv8;
        *(bf16x8*)&As2[1][row * 128 + s * 8] = lv8;
    }
    __syncthreads();

    f32x4 acc[6][4];
    #pragma unroll
    for (int cf = 0; cf < 6; ++cf)
        #pragma unroll
        for (int rf = 0; rf < 4; ++rf)
            acc[cf][rf] = (f32x4){0.f, 0.f, 0.f, 0.f};

    int wrow[6];
    #pragma unroll
    for (int cf = 0; cf < 6; ++cf) {
        int col  = colbase + cf * 16 + r;
        int j    = col >> 7;
        int pcol = col & 127;
        int o    = ((pcol & 15) << 3) | (pcol >> 4);
        wrow[cf] = (j * 128 + o) * 128;
    }

    #pragma unroll
    for (int t = 0; t < 4; ++t) {
        int k0   = t * 32 + kg * 8;
        int slot = t * 4 + kg;
        // W fragment loads first (independent; latency hidden by other waves'
        // MFMA clusters and this step's ds_reads)
        bf16x8 bh[6], bl[6];
        #pragma unroll
        for (int cf = 0; cf < 6; ++cf) {
            bh[cf] = *(const bf16x8*)&Whi[wrow[cf] + k0];
            bl[cf] = *(const bf16x8*)&Wlo[wrow[cf] + k0];
        }
        // A fragments: pure ds_read_b128, no conversion
        bf16x8 ah[4], al[4];
        #pragma unroll
        for (int rf = 0; rf < 4; ++rf) {
            int row = rf * 16 + r;
            int s2  = slot ^ (r & 7);
            ah[rf] = *(bf16x8*)&As2[0][row * 128 + s2 * 8];
            al[rf] = *(bf16x8*)&As2[1][row * 128 + s2 * 8];
        }
        // 72-MFMA cluster
        #pragma unroll
        for (int cf = 0; cf < 6; ++cf) {
            #pragma unroll
            for (int rf = 0; rf < 4; ++rf) {
                acc[cf][rf] = __builtin_amdgcn_mfma_f32_16x16x32_bf16(ah[rf], bh[cf], acc[cf][rf], 0, 0, 0);
                acc[cf][rf] = __builtin_amdgcn_mfma_f32_16x16x32_bf16(al[rf], bh[cf], acc[cf][rf], 0, 0, 0);
                acc[cf][rf] = __builtin_amdgcn_mfma_f32_16x16x32_bf16(ah[rf], bl[cf], acc[cf][rf], 0, 0, 0);
            }
        }
    }

    // ---- epilogue: q direct; kv through LDS for coalesced stores ----
    __syncthreads();                        // all As reads done; reuse buffer
    __bf16* kvs = &As2[0][0];               // 64 x 256 bf16 = 32 KB
    int orow = kg * 4;
    #pragma unroll
    for (int cf = 0; cf < 6; ++cf) {
        int col  = colbase + cf * 16 + r;
        int j    = col >> 7;                // 0=q 1=k 2=v (uniform per cf)
        int pcol = col & 127;
        float b  = bias384[col];
        #pragma unroll
        for (int rf = 0; rf < 4; ++rf) {
            #pragma unroll
            for (int e = 0; e < 4; ++e) {
                int mrow = rf * 16 + orow + e;      // 0..63
                float val = acc[cf][rf][e] + b;
                if (j == 0) {
                    int mg = m0 + mrow;
                    if (mg < M) q[(size_t)mg * 128 + pcol] = val;
                } else {
                    int gi  = pcol >> 2;
                    int idx = gi * 8 + ((j == 1) ? 0 : 4) + (pcol & 3);
                    kvs[mrow * 256 + idx] = (__bf16)val;
                }
            }
        }
    }
    __syncthreads();
    #pragma unroll
    for (int it = 0; it < 8; ++it) {
        int flat = it * 256 + tid;          // 16B chunk 0..2047
        int row  = flat >> 5;
        int c    = flat & 31;
        int mg   = m0 + row;
        if (mg < M)
            *(uint4*)&kv[(size_t)mg * 256 + c * 8] = *(uint4*)&kvs[row * 256 + c * 8];
    }
}

// ---------------------------------------------------------------------------
// Kernel 3: fused SDDMM + online segment-softmax + SPMM (unchanged).
// ---------------------------------------------------------------------------
__device__ __forceinline__ float blo(unsigned u) { return __uint_as_float(u << 16); }
__device__ __forceinline__ float bhi(unsigned u) { return __uint_as_float(u & 0xffff0000u); }

__global__ __launch_bounds__(256)
void edge_attn_kernel(const int* __restrict__ row_ptr, const int* __restrict__ col,
                      const float* __restrict__ q, const __bf16* __restrict__ kv,
                      float* __restrict__ out, int N_) {
    int wave = threadIdx.x >> 6;
    int lane = threadIdx.x & 63;
    int node = blockIdx.x * 4 + wave;
    if (node >= N_) return;
    int sl   = lane & 31;
    int half = lane >> 5;

    float4 q4 = *(const float4*)&q[(size_t)node * 128 + sl * 4];
    int e0 = row_ptr[node];
    int e1 = row_ptr[node + 1];

    float m = -INFINITY, z = 0.f;
    float4 acc = make_float4(0.f, 0.f, 0.f, 0.f);

    auto score = [&](uint4 u) {
        float p = q4.x * blo(u.x) + q4.y * bhi(u.x) +
                  q4.z * blo(u.y) + q4.w * bhi(u.y);
        p += __shfl_xor(p, 1);
        p += __shfl_xor(p, 2);
        return p * 0.25f;                       // 1/sqrt(DH)
    };
    auto update = [&](float s, uint4 u) {
        float mnew  = fmaxf(m, s);
        float alpha = __expf(m - mnew);
        float w     = __expf(s - mnew);
        z = z * alpha + w;
        acc.x = acc.x * alpha + w * blo(u.z);
        acc.y = acc.y * alpha + w * bhi(u.z);
        acc.z = acc.z * alpha + w * blo(u.w);
        acc.w = acc.w * alpha + w * bhi(u.w);
        m = mnew;
    };

    int eb = e0;
    for (; eb + 4 <= e1; eb += 4) {
        int ea = eb + half * 2;
        int c0 = col[ea];
        int c1 = col[ea + 1];
        uint4 u0 = *(const uint4*)(kv + (size_t)c0 * 256 + sl * 8);
        uint4 u1 = *(const uint4*)(kv + (size_t)c1 * 256 + sl * 8);
        float s0 = score(u0);
        float s1 = score(u1);
        update(s0, u0);
        update(s1, u1);
    }
    for (; eb < e1; eb += 2) {
        int my_e   = eb + half;
        bool valid = (my_e < e1);
        int cnode  = valid ? col[my_e] : col[eb];
        uint4 u = *(const uint4*)(kv + (size_t)cnode * 256 + sl * 8);
        float s = valid ? score(u) : -INFINITY;
        float mnew = fmaxf(m, s);
        if (mnew > -INFINITY) {
            float alpha = __expf(m - mnew);
            float w     = __expf(s - mnew);
            z = z * alpha + w;
            acc.x = acc.x * alpha + w * blo(u.z);
            acc.y = acc.y * alpha + w * bhi(u.z);
            acc.z = acc.z * alpha + w * blo(u.w);
            acc.w = acc.w * alpha + w * bhi(u.w);
            m = mnew;
        }
    }

    float m2 = __shfl_xor(m, 32);
    float z2 = __shfl_xor(z, 32);
    float ax = __shfl_xor(acc.x, 32);
    float ay = __shfl_xor(acc.y, 32);
    float az = __shfl_xor(acc.z, 32);
    float aw = __shfl_xor(acc.w, 32);
    float mm = fmaxf(m, m2);
    if (mm > -INFINITY) {
        float a1 = __expf(m - mm);
        float a2 = __expf(m2 - mm);
        z = z * a1 + z2 * a2;
        acc.x = acc.x * a1 + ax * a2;
        acc.y = acc.y * a1 + ay * a2;
        acc.z = acc.z * a1 + az * a2;
        acc.w = acc.w * a1 + aw * a2;
    }

    if (half == 0) {
        float inv = (z > 0.f) ? 1.0f / z : 0.f;
        float rr[4] = {acc.x * inv, acc.y * inv, acc.z * inv, acc.w * inv};
        #pragma unroll
        for (int jj = 0; jj < 4; ++jj) {
            int cp = sl * 4 + jj;
            int d  = cp & 15;
            int hd = cp >> 4;
            out[(size_t)node * HID + d * 8 + hd] = rr[jj];
        }
    }
}

// ---------------------------------------------------------------------------
// Kernel 4: output projection via MFMA hi/lo split; 64-row tiles; A presplit
// at staging (same schedule as kernel 2), 4 waves x 32 cols.
// ---------------------------------------------------------------------------
__global__ __launch_bounds__(256)
void outproj_mfma_kernel(const float* __restrict__ A, int M,
                         const __bf16* __restrict__ Whi, const __bf16* __restrict__ Wlo,
                         const float* __restrict__ bo, float* __restrict__ C) {
    __shared__ __bf16 As2[2][64 * 128];
    int tid  = threadIdx.x;
    int wv   = tid >> 6;
    int lane = tid & 63;
    int r    = lane & 15;
    int kg   = lane >> 4;
    int m0   = blockIdx.x * 64;
    int colbase = wv * 32;

    #pragma unroll
    for (int it = 0; it < 4; ++it) {
        int flat = it * 256 + tid;
        int row  = flat >> 4;
        int s    = flat & 15;
        int g    = s ^ (row & 7);
        int grow = m0 + row; if (grow > M - 1) grow = M - 1;
        const float* src = &A[(size_t)grow * 128 + g * 8];
        float4 x0 = *(const float4*)src;
        float4 x1 = *(const float4*)(src + 4);
        float xs[8] = {x0.x, x0.y, x0.z, x0.w, x1.x, x1.y, x1.z, x1.w};
        bf16x8 hv8, lv8;
        #pragma unroll
        for (int e = 0; e < 8; ++e) {
            __bf16 hv = (__bf16)xs[e];
            hv8[e] = hv;
            lv8[e] = (__bf16)(xs[e] - (float)hv);
        }
        *(bf16x8*)&As2[0][row * 128 + s * 8] = hv8;
        *(bf16x8*)&As2[1][row * 128 + s * 8] = lv8;
    }
    __syncthreads();

    f32x4 acc[2][4];
    #pragma unroll
    for (int cf = 0; cf < 2; ++cf)
        #pragma unroll
        for (int rf = 0; rf < 4; ++rf)
            acc[cf][rf] = (f32x4){0.f, 0.f, 0.f, 0.f};

    #pragma unroll
    for (int t = 0; t < 4; ++t) {
        int k0   = t * 32 + kg * 8;
        int slot = t * 4 + kg;
        bf16x8 bh[2], bl[2];
        #pragma unroll
        for (int cf = 0; cf < 2; ++cf) {
            int wrow = (colbase + cf * 16 + r) * 128;
            bh[cf] = *(const bf16x8*)&Whi[wrow + k0];
            bl[cf] = *(const bf16x8*)&Wlo[wrow + k0];
        }
        bf16x8 ah[4], al[4];
        #pragma unroll
        for (int rf = 0; rf < 4; ++rf) {
            int row = rf * 16 + r;
            int s2  = slot ^ (r & 7);
            ah[rf] = *(bf16x8*)&As2[0][row * 128 + s2 * 8];
            al[rf] = *(bf16x8*)&As2[1][row * 128 + s2 * 8];
        }
        #pragma unroll
        for (int cf = 0; cf < 2; ++cf) {
            #pragma unroll
            for (int rf = 0; rf < 4; ++rf) {
                acc[cf][rf] = __builtin_amdgcn_mfma_f32_16x16x32_bf16(ah[rf], bh[cf], acc[cf][rf], 0, 0, 0);
                acc[cf][rf] = __builtin_amdgcn_mfma_f32_16x16x32_bf16(al[rf], bh[cf], acc[cf][rf], 0, 0, 0);
                acc[cf][rf] = __builtin_amdgcn_mfma_f32_16x16x32_bf16(ah[rf], bl[cf], acc[cf][rf], 0, 0, 0);
            }
        }
    }

    int orow = kg * 4;
    #pragma unroll
    for (int cf = 0; cf < 2; ++cf) {
        int col = colbase + cf * 16 + r;
        float b = bo[col];
        #pragma unroll
        for (int rf = 0; rf < 4; ++rf) {
            #pragma unroll
            for (int e = 0; e < 4; ++e) {
                int mg = m0 + rf * 16 + orow + e;
                if (mg < M) C[(size_t)mg * HID + col] = acc[cf][rf][e] + b;
            }
        }
    }
}

// ---------------------------------------------------------------------------
extern "C" void kernel_launch(void* const* d_in, const int* in_sizes, int n_in,
                              void* d_out, int out_size, void* d_ws, size_t ws_size,
                              hipStream_t stream) {
    const float* h  = (const float*)d_in[0];
    const int* row  = (const int*)d_in[1];
    const int* col  = (const int*)d_in[2];
    const float* Wq = (const float*)d_in[3];
    const float* bq = (const float*)d_in[4];
    const float* Wk = (const float*)d_in[5];
    const float* bk = (const float*)d_in[6];
    const float* Wv = (const float*)d_in[7];
    const float* bv = (const float*)d_in[8];
    const float* Wo = (const float*)d_in[9];
    const float* bo = (const float*)d_in[10];
    float* out = (float*)d_out;

    int N_ = in_sizes[0] / HID;   // 50000
    int E_ = in_sizes[1];         // 800000

    char* ws = (char*)d_ws;
    size_t off = 0;
    auto alloc = [&](size_t bytes) {
        void* p = (void*)(ws + off);
        off = (off + bytes + 255) & ~(size_t)255;
        return p;
    };
    int*    row_ptr = (int*)   alloc((size_t)(N_ + 1) * sizeof(int));
    float*  qb      = (float*) alloc((size_t)N_ * 128 * sizeof(float));
    __bf16* kvb     = (__bf16*)alloc((size_t)N_ * 256 * sizeof(__bf16));
    float*  ob      = (float*) alloc((size_t)N_ * HID * sizeof(float));
    __bf16* Whi     = (__bf16*)alloc((size_t)4 * 16384 * sizeof(__bf16));
    __bf16* Wlo     = (__bf16*)alloc((size_t)4 * 16384 * sizeof(__bf16));
    float*  bias384 = (float*) alloc(384 * sizeof(float));
    (void)ws_size;

    prep_kernel<<<256, 256, 0, stream>>>(row, row_ptr, N_, E_,
                                         Wq, Wk, Wv, Wo, bq, bk, bv,
                                         Whi, Wlo, bias384);
    qkv_mfma_kernel<<<(N_ + 63) / 64, 256, 0, stream>>>(h, N_, Whi, Wlo, bias384, qb, kvb);
    edge_attn_kernel<<<(N_ + 3) / 4, 256, 0, stream>>>(row_ptr, col, qb, kvb, ob, N_);
    outproj_mfma_kernel<<<(N_ + 63) / 64, 256, 0, stream>>>(
        ob, N_, Whi + 3 * 16384, Wlo + 3 * 16384, bo, out);
}

// Round 7
// 204.809 us; speedup vs baseline: 1.1349x; 1.0578x over previous
//
#include <hip/hip_runtime.h>
#include <hip/hip_bf16.h>
#include <math.h>

#define HID 128
#define NH 8
#define DH 16

typedef __bf16 bf16x8 __attribute__((ext_vector_type(8)));
typedef __bf16 bf16x4 __attribute__((ext_vector_type(4)));
typedef float  f32x4  __attribute__((ext_vector_type(4)));

// ---------------------------------------------------------------------------
// Kernel 1 (prep): rowptr binary-search + W hi/lo split + bias384.
// Wq/Wk/Wv stored natural-K; Wo stored with K-dim head-major-permuted so the
// output projection can consume ob in head-major order directly.
// ---------------------------------------------------------------------------
__global__ void prep_kernel(const int* __restrict__ row, int* __restrict__ row_ptr,
                            int N_, int E_,
                            const float* __restrict__ Wq, const float* __restrict__ Wk,
                            const float* __restrict__ Wv, const float* __restrict__ Wo,
                            const float* __restrict__ bq, const float* __restrict__ bk,
                            const float* __restrict__ bv,
                            __bf16* __restrict__ Whi, __bf16* __restrict__ Wlo,
                            float* __restrict__ bias384) {
    int idx = blockIdx.x * blockDim.x + threadIdx.x;
    if (idx < 4 * 16384) {
        int j = idx >> 14;
        int rem = idx & 16383;
        float x;
        if (j < 3) {
            const float* W = (j == 0) ? Wq : (j == 1) ? Wk : Wv;
            x = W[rem];
        } else {
            int o  = rem >> 7;
            int kp = rem & 127;                      // head-major K index
            int k  = ((kp & 15) << 3) | (kp >> 4);   // reference channel
            x = Wo[o * 128 + k];
        }
        __bf16 hv = (__bf16)x;
        Whi[idx] = hv;
        Wlo[idx] = (__bf16)(x - (float)hv);
    }
    if (idx <= N_) {
        int lo = 0, hi = E_;
        while (lo < hi) {
            int mid = (lo + hi) >> 1;
            if (row[mid] < idx) lo = mid + 1; else hi = mid;
        }
        row_ptr[idx] = lo;
    }
    if (idx < 384) {
        int j = idx >> 7;
        int pcol = idx & 127;                       // head-major col within proj
        int o = ((pcol & 15) << 3) | (pcol >> 4);   // original W row
        const float* b = (j == 0) ? bq : (j == 1) ? bk : bv;
        bias384[idx] = b[o];
    }
}

// ---------------------------------------------------------------------------
// Kernel 2: QKV projection via MFMA (2-term hi/lo split).
// Grid (M/64, 2): blockIdx.y picks the head-major col half [by*64, by*64+64)
// of EACH of q,k,v -> 192 fused cols per block, 4 waves x 48 cols (3 frags).
// A presplit to bf16 hi/lo at staging, XOR-swizzled LDS.  Per k-step:
// 6 W loads, 8 ds_read_b128, 24 MFMAs (Ahi*Bh + Alo*Bh; Ahi*Bl dropped).
// q fp32 [N][128] head-major; k,v bf16 interleaved kv[N][256]; this block
// owns whole 16B groups [by*16, by*16+16) -> coalesced uint4 stores.
// ---------------------------------------------------------------------------
__global__ __launch_bounds__(256)
void qkv_mfma_kernel(const float* __restrict__ h, int M,
                     const __bf16* __restrict__ Whi, const __bf16* __restrict__ Wlo,
                     const float* __restrict__ bias384,
                     float* __restrict__ q, __bf16* __restrict__ kv) {
    __shared__ __bf16 As2[2][64 * 128];     // [0]=hi, [1]=lo; 32 KB
    int tid  = threadIdx.x;
    int wv   = tid >> 6;
    int lane = tid & 63;
    int r    = lane & 15;
    int kg   = lane >> 4;
    int m0   = blockIdx.x * 64;
    int by   = blockIdx.y;                  // col half

    // ---- stage A: coalesced 32B reads, hi/lo split, swizzled slots ----
    #pragma unroll
    for (int it = 0; it < 4; ++it) {
        int flat = it * 256 + tid;          // 16B-slot task 0..1023
        int row  = flat >> 4;               // 0..63
        int s    = flat & 15;               // LDS slot
        int g    = s ^ (row & 7);           // global slot (involution)
        int grow = m0 + row; if (grow > M - 1) grow = M - 1;
        const float* src = &h[(size_t)grow * 128 + g * 8];
        float4 x0 = *(const float4*)src;
        float4 x1 = *(const float4*)(src + 4);
        float xs[8] = {x0.x, x0.y, x0.z, x0.w, x1.x, x1.y, x1.z, x1.w};
        bf16x8 hv8, lv8;
        #pragma unroll
        for (int e = 0; e < 8; ++e) {
            __bf16 hv = (__bf16)xs[e];
            hv8[e] = hv;
            lv8[e] = (__bf16)(xs[e] - (float)hv);
        }
        *(bf16x8*)&As2[0][row * 128 + s * 8] = hv8;
        *(bf16x8*)&As2[1][row * 128 + s * 8] = lv8;
    }
    __syncthreads();

    f32x4 acc[3][4];
    #pragma unroll
    for (int cf = 0; cf < 3; ++cf)
        #pragma unroll
        for (int rf = 0; rf < 4; ++rf)
            acc[cf][rf] = (f32x4){0.f, 0.f, 0.f, 0.f};

    int wrow[3], jseg[3], pcb[3];
    #pragma unroll
    for (int cf = 0; cf < 3; ++cf) {
        int fb   = wv * 48 + cf * 16;       // fragment base within 192
        int seg  = fb >> 6;                 // 0=q 1=k 2=v
        int pcol = by * 64 + (fb & 63) + r; // head-major col within proj
        int o    = ((pcol & 15) << 3) | (pcol >> 4);
        wrow[cf] = (seg * 128 + o) * 128;
        jseg[cf] = seg;
        pcb[cf]  = pcol;
    }

    #pragma unroll
    for (int t = 0; t < 4; ++t) {
        int k0   = t * 32 + kg * 8;
        int slot = t * 4 + kg;
        bf16x8 bh[3], bl[3];
        #pragma unroll
        for (int cf = 0; cf < 3; ++cf) {
            bh[cf] = *(const bf16x8*)&Whi[wrow[cf] + k0];
            bl[cf] = *(const bf16x8*)&Wlo[wrow[cf] + k0];
        }
        bf16x8 ah[4], al[4];
        #pragma unroll
        for (int rf = 0; rf < 4; ++rf) {
            int row = rf * 16 + r;
            int s2  = slot ^ (r & 7);
            ah[rf] = *(bf16x8*)&As2[0][row * 128 + s2 * 8];
            al[rf] = *(bf16x8*)&As2[1][row * 128 + s2 * 8];
        }
        #pragma unroll
        for (int cf = 0; cf < 3; ++cf) {
            #pragma unroll
            for (int rf = 0; rf < 4; ++rf) {
                acc[cf][rf] = __builtin_amdgcn_mfma_f32_16x16x32_bf16(ah[rf], bh[cf], acc[cf][rf], 0, 0, 0);
                acc[cf][rf] = __builtin_amdgcn_mfma_f32_16x16x32_bf16(al[rf], bh[cf], acc[cf][rf], 0, 0, 0);
            }
        }
    }

    // ---- epilogue: q direct; kv through LDS (full 16B groups) ----
    __syncthreads();
    __bf16* kvs = &As2[0][0];               // 64 x 128 bf16 = 16 KB
    int orow = kg * 4;
    #pragma unroll
    for (int cf = 0; cf < 3; ++cf) {
        int j    = jseg[cf];
        int pcol = pcb[cf];
        float b  = bias384[j * 128 + pcol];
        #pragma unroll
        for (int rf = 0; rf < 4; ++rf) {
            #pragma unroll
            for (int e = 0; e < 4; ++e) {
                int mrow = rf * 16 + orow + e;      // 0..63
                float val = acc[cf][rf][e] + b;
                if (j == 0) {
                    int mg = m0 + mrow;
                    if (mg < M) q[(size_t)mg * 128 + pcol] = val;
                } else {
                    int gl  = (pcol & 63) >> 2;     // local group 0..15
                    int idx = gl * 8 + ((j == 1) ? 0 : 4) + (pcol & 3);
                    kvs[mrow * 128 + idx] = (__bf16)val;
                }
            }
        }
    }
    __syncthreads();
    #pragma unroll
    for (int it = 0; it < 4; ++it) {
        int flat = it * 256 + tid;          // 16B chunk 0..1023
        int row  = flat >> 4;               // 0..63
        int u    = flat & 15;               // group within half
        int mg   = m0 + row;
        if (mg < M)
            *(uint4*)&kv[(size_t)mg * 256 + by * 128 + u * 8] =
                *(uint4*)&kvs[row * 128 + u * 8];
    }
}

// ---------------------------------------------------------------------------
// Kernel 3: fused SDDMM + online segment-softmax + SPMM.
// Epilogue now writes ob as presplit bf16 hi/lo in HEAD-MAJOR order
// (coalesced bf16x4 stores, no permute) for the output projection.
// ---------------------------------------------------------------------------
__device__ __forceinline__ float blo(unsigned u) { return __uint_as_float(u << 16); }
__device__ __forceinline__ float bhi(unsigned u) { return __uint_as_float(u & 0xffff0000u); }

__global__ __launch_bounds__(256)
void edge_attn_kernel(const int* __restrict__ row_ptr, const int* __restrict__ col,
                      const float* __restrict__ q, const __bf16* __restrict__ kv,
                      __bf16* __restrict__ obhi, __bf16* __restrict__ oblo, int N_) {
    int wave = threadIdx.x >> 6;
    int lane = threadIdx.x & 63;
    int node = blockIdx.x * 4 + wave;
    if (node >= N_) return;
    int sl   = lane & 31;
    int half = lane >> 5;

    float4 q4 = *(const float4*)&q[(size_t)node * 128 + sl * 4];
    int e0 = row_ptr[node];
    int e1 = row_ptr[node + 1];

    float m = -INFINITY, z = 0.f;
    float4 acc = make_float4(0.f, 0.f, 0.f, 0.f);

    auto score = [&](uint4 u) {
        float p = q4.x * blo(u.x) + q4.y * bhi(u.x) +
                  q4.z * blo(u.y) + q4.w * bhi(u.y);
        p += __shfl_xor(p, 1);
        p += __shfl_xor(p, 2);
        return p * 0.25f;                       // 1/sqrt(DH)
    };
    auto update = [&](float s, uint4 u) {
        float mnew  = fmaxf(m, s);
        float alpha = __expf(m - mnew);
        float w     = __expf(s - mnew);
        z = z * alpha + w;
        acc.x = acc.x * alpha + w * blo(u.z);
        acc.y = acc.y * alpha + w * bhi(u.z);
        acc.z = acc.z * alpha + w * blo(u.w);
        acc.w = acc.w * alpha + w * bhi(u.w);
        m = mnew;
    };

    int eb = e0;
    for (; eb + 4 <= e1; eb += 4) {
        int ea = eb + half * 2;
        int c0 = col[ea];
        int c1 = col[ea + 1];
        uint4 u0 = *(const uint4*)(kv + (size_t)c0 * 256 + sl * 8);
        uint4 u1 = *(const uint4*)(kv + (size_t)c1 * 256 + sl * 8);
        float s0 = score(u0);
        float s1 = score(u1);
        update(s0, u0);
        update(s1, u1);
    }
    for (; eb < e1; eb += 2) {
        int my_e   = eb + half;
        bool valid = (my_e < e1);
        int cnode  = valid ? col[my_e] : col[eb];
        uint4 u = *(const uint4*)(kv + (size_t)cnode * 256 + sl * 8);
        float s = valid ? score(u) : -INFINITY;
        float mnew = fmaxf(m, s);
        if (mnew > -INFINITY) {
            float alpha = __expf(m - mnew);
            float w     = __expf(s - mnew);
            z = z * alpha + w;
            acc.x = acc.x * alpha + w * blo(u.z);
            acc.y = acc.y * alpha + w * bhi(u.z);
            acc.z = acc.z * alpha + w * blo(u.w);
            acc.w = acc.w * alpha + w * bhi(u.w);
            m = mnew;
        }
    }

    float m2 = __shfl_xor(m, 32);
    float z2 = __shfl_xor(z, 32);
    float ax = __shfl_xor(acc.x, 32);
    float ay = __shfl_xor(acc.y, 32);
    float az = __shfl_xor(acc.z, 32);
    float aw = __shfl_xor(acc.w, 32);
    float mm = fmaxf(m, m2);
    if (mm > -INFINITY) {
        float a1 = __expf(m - mm);
        float a2 = __expf(m2 - mm);
        z = z * a1 + z2 * a2;
        acc.x = acc.x * a1 + ax * a2;
        acc.y = acc.y * a1 + ay * a2;
        acc.z = acc.z * a1 + az * a2;
        acc.w = acc.w * a1 + aw * a2;
    }

    if (half == 0) {
        float inv = (z > 0.f) ? 1.0f / z : 0.f;
        float rr[4] = {acc.x * inv, acc.y * inv, acc.z * inv, acc.w * inv};
        bf16x4 hv4, lv4;
        #pragma unroll
        for (int jj = 0; jj < 4; ++jj) {
            __bf16 hv = (__bf16)rr[jj];
            hv4[jj] = hv;
            lv4[jj] = (__bf16)(rr[jj] - (float)hv);
        }
        *(bf16x4*)&obhi[(size_t)node * 128 + sl * 4] = hv4;   // head-major
        *(bf16x4*)&oblo[(size_t)node * 128 + sl * 4] = lv4;
    }
}

// ---------------------------------------------------------------------------
// Kernel 4: output projection.  A arrives presplit bf16 hi/lo head-major;
// Wo's K-dim was permuted at prep, so no conversion, no permute here.
// Grid (M/64, 2): by = output-col half; 4 waves x 16 cols (1 fragment).
// ---------------------------------------------------------------------------
__global__ __launch_bounds__(256)
void outproj_mfma_kernel(const __bf16* __restrict__ Ahi_g, const __bf16* __restrict__ Alo_g,
                         int M, const __bf16* __restrict__ Whi, const __bf16* __restrict__ Wlo,
                         const float* __restrict__ bo, float* __restrict__ C) {
    __shared__ __bf16 As2[2][64 * 128];
    int tid  = threadIdx.x;
    int wv   = tid >> 6;
    int lane = tid & 63;
    int r    = lane & 15;
    int kg   = lane >> 4;
    int m0   = blockIdx.x * 64;
    int by   = blockIdx.y;
    int col  = by * 64 + wv * 16 + r;       // output column (natural)

    #pragma unroll
    for (int it = 0; it < 4; ++it) {
        int flat = it * 256 + tid;
        int row  = flat >> 4;
        int s    = flat & 15;
        int g    = s ^ (row & 7);
        int grow = m0 + row; if (grow > M - 1) grow = M - 1;
        *(bf16x8*)&As2[0][row * 128 + s * 8] = *(const bf16x8*)&Ahi_g[(size_t)grow * 128 + g * 8];
        *(bf16x8*)&As2[1][row * 128 + s * 8] = *(const bf16x8*)&Alo_g[(size_t)grow * 128 + g * 8];
    }
    __syncthreads();

    f32x4 acc[4];
    #pragma unroll
    for (int rf = 0; rf < 4; ++rf) acc[rf] = (f32x4){0.f, 0.f, 0.f, 0.f};

    int wrow = col * 128;
    #pragma unroll
    for (int t = 0; t < 4; ++t) {
        int k0   = t * 32 + kg * 8;
        int slot = t * 4 + kg;
        bf16x8 bh = *(const bf16x8*)&Whi[wrow + k0];
        bf16x8 bl = *(const bf16x8*)&Wlo[wrow + k0];
        bf16x8 ah[4], al[4];
        #pragma unroll
        for (int rf = 0; rf < 4; ++rf) {
            int row = rf * 16 + r;
            int s2  = slot ^ (r & 7);
            ah[rf] = *(bf16x8*)&As2[0][row * 128 + s2 * 8];
            al[rf] = *(bf16x8*)&As2[1][row * 128 + s2 * 8];
        }
        #pragma unroll
        for (int rf = 0; rf < 4; ++rf) {
            acc[rf] = __builtin_amdgcn_mfma_f32_16x16x32_bf16(ah[rf], bh, acc[rf], 0, 0, 0);
            acc[rf] = __builtin_amdgcn_mfma_f32_16x16x32_bf16(al[rf], bh, acc[rf], 0, 0, 0);
        }
    }

    float b = bo[col];
    #pragma unroll
    for (int rf = 0; rf < 4; ++rf) {
        #pragma unroll
        for (int e = 0; e < 4; ++e) {
            int mg = m0 + rf * 16 + kg * 4 + e;
            if (mg < M) C[(size_t)mg * 128 + col] = acc[rf][e] + b;
        }
    }
}

// ---------------------------------------------------------------------------
extern "C" void kernel_launch(void* const* d_in, const int* in_sizes, int n_in,
                              void* d_out, int out_size, void* d_ws, size_t ws_size,
                              hipStream_t stream) {
    const float* h  = (const float*)d_in[0];
    const int* row  = (const int*)d_in[1];
    const int* col  = (const int*)d_in[2];
    const float* Wq = (const float*)d_in[3];
    const float* bq = (const float*)d_in[4];
    const float* Wk = (const float*)d_in[5];
    const float* bk = (const float*)d_in[6];
    const float* Wv = (const float*)d_in[7];
    const float* bv = (const float*)d_in[8];
    const float* Wo = (const float*)d_in[9];
    const float* bo = (const float*)d_in[10];
    float* out = (float*)d_out;

    int N_ = in_sizes[0] / HID;   // 50000
    int E_ = in_sizes[1];         // 800000

    char* ws = (char*)d_ws;
    size_t off = 0;
    auto alloc = [&](size_t bytes) {
        void* p = (void*)(ws + off);
        off = (off + bytes + 255) & ~(size_t)255;
        return p;
    };
    int*    row_ptr = (int*)   alloc((size_t)(N_ + 1) * sizeof(int));
    float*  qb      = (float*) alloc((size_t)N_ * 128 * sizeof(float));
    __bf16* kvb     = (__bf16*)alloc((size_t)N_ * 256 * sizeof(__bf16));
    __bf16* obhi    = (__bf16*)alloc((size_t)N_ * 128 * sizeof(__bf16));
    __bf16* oblo    = (__bf16*)alloc((size_t)N_ * 128 * sizeof(__bf16));
    __bf16* Whi     = (__bf16*)alloc((size_t)4 * 16384 * sizeof(__bf16));
    __bf16* Wlo     = (__bf16*)alloc((size_t)4 * 16384 * sizeof(__bf16));
    float*  bias384 = (float*) alloc(384 * sizeof(float));
    (void)ws_size;

    prep_kernel<<<256, 256, 0, stream>>>(row, row_ptr, N_, E_,
                                         Wq, Wk, Wv, Wo, bq, bk, bv,
                                         Whi, Wlo, bias384);
    qkv_mfma_kernel<<<dim3((N_ + 63) / 64, 2), 256, 0, stream>>>(
        h, N_, Whi, Wlo, bias384, qb, kvb);
    edge_attn_kernel<<<(N_ + 3) / 4, 256, 0, stream>>>(row_ptr, col, qb, kvb, obhi, oblo, N_);
    outproj_mfma_kernel<<<dim3((N_ + 63) / 64, 2), 256, 0, stream>>>(
        obhi, oblo, N_, Whi + 3 * 16384, Wlo + 3 * 16384, bo, out);
}

// Round 8
// 192.212 us; speedup vs baseline: 1.2092x; 1.0655x over previous
//
#include <hip/hip_runtime.h>
#include <hip/hip_bf16.h>
#include <math.h>

#define HID 128
#define NH 8
#define DH 16

typedef __bf16 bf16x8 __attribute__((ext_vector_type(8)));
typedef __bf16 bf16x4 __attribute__((ext_vector_type(4)));
typedef float  f32x4  __attribute__((ext_vector_type(4)));

// ---------------------------------------------------------------------------
// Kernel 1 (prep): rowptr binary-search + W -> bf16 cast + bias384.
// Wq/Wk/Wv natural-K; Wo K-dim head-major-permuted (consumes ob head-major).
// ---------------------------------------------------------------------------
__global__ void prep_kernel(const int* __restrict__ row, int* __restrict__ row_ptr,
                            int N_, int E_,
                            const float* __restrict__ Wq, const float* __restrict__ Wk,
                            const float* __restrict__ Wv, const float* __restrict__ Wo,
                            const float* __restrict__ bq, const float* __restrict__ bk,
                            const float* __restrict__ bv,
                            __bf16* __restrict__ Whi, float* __restrict__ bias384) {
    int idx = blockIdx.x * blockDim.x + threadIdx.x;
    if (idx < 4 * 16384) {
        int j = idx >> 14;
        int rem = idx & 16383;
        float x;
        if (j < 3) {
            const float* W = (j == 0) ? Wq : (j == 1) ? Wk : Wv;
            x = W[rem];
        } else {
            int o  = rem >> 7;
            int kp = rem & 127;                      // head-major K index
            int k  = ((kp & 15) << 3) | (kp >> 4);   // reference channel
            x = Wo[o * 128 + k];
        }
        Whi[idx] = (__bf16)x;
    }
    if (idx <= N_) {
        int lo = 0, hi = E_;
        while (lo < hi) {
            int mid = (lo + hi) >> 1;
            if (row[mid] < idx) lo = mid + 1; else hi = mid;
        }
        row_ptr[idx] = lo;
    }
    if (idx < 384) {
        int j = idx >> 7;
        int pcol = idx & 127;                       // head-major col within proj
        int o = ((pcol & 15) << 3) | (pcol >> 4);   // original W row
        const float* b = (j == 0) ? bq : (j == 1) ? bk : bv;
        bias384[idx] = b[o];
    }
}

// ---------------------------------------------------------------------------
// Kernel 2: QKV projection, single-term bf16 MFMA.
// Grid (M/64, 2): by = head-major col half of each of q,k,v -> 192 fused
// cols/block, 4 waves x 48 cols (3 frags).  A cast to bf16 at staging,
// XOR-swizzled 16 KB LDS.  Per k-step: 3 W loads, 4 ds_read_b128, 12 MFMA.
// q bf16 [N][128] head-major; k,v bf16 interleaved kv[N][256] via LDS
// transpose (As reused) -> coalesced uint4 stores.
// ---------------------------------------------------------------------------
__global__ __launch_bounds__(256)
void qkv_mfma_kernel(const float* __restrict__ h, int M,
                     const __bf16* __restrict__ Whi,
                     const float* __restrict__ bias384,
                     __bf16* __restrict__ q, __bf16* __restrict__ kv) {
    __shared__ __bf16 As[64 * 128];         // 16 KB; reused as kv buffer
    int tid  = threadIdx.x;
    int wv   = tid >> 6;
    int lane = tid & 63;
    int r    = lane & 15;
    int kg   = lane >> 4;
    int m0   = blockIdx.x * 64;
    int by   = blockIdx.y;                  // col half

    // ---- stage A: coalesced 32B reads, bf16 cast, swizzled 16B slots ----
    #pragma unroll
    for (int it = 0; it < 4; ++it) {
        int flat = it * 256 + tid;          // 16B-slot task 0..1023
        int row  = flat >> 4;               // 0..63
        int s    = flat & 15;               // LDS slot
        int g    = s ^ (row & 7);           // global slot (involution)
        int grow = m0 + row; if (grow > M - 1) grow = M - 1;
        const float* src = &h[(size_t)grow * 128 + g * 8];
        float4 x0 = *(const float4*)src;
        float4 x1 = *(const float4*)(src + 4);
        float xs[8] = {x0.x, x0.y, x0.z, x0.w, x1.x, x1.y, x1.z, x1.w};
        bf16x8 hv8;
        #pragma unroll
        for (int e = 0; e < 8; ++e) hv8[e] = (__bf16)xs[e];
        *(bf16x8*)&As[row * 128 + s * 8] = hv8;
    }
    __syncthreads();

    f32x4 acc[3][4];
    #pragma unroll
    for (int cf = 0; cf < 3; ++cf)
        #pragma unroll
        for (int rf = 0; rf < 4; ++rf)
            acc[cf][rf] = (f32x4){0.f, 0.f, 0.f, 0.f};

    int wrow[3], jseg[3], pcb[3];
    #pragma unroll
    for (int cf = 0; cf < 3; ++cf) {
        int fb   = wv * 48 + cf * 16;       // fragment base within 192
        int seg  = fb >> 6;                 // 0=q 1=k 2=v
        int pcol = by * 64 + (fb & 63) + r; // head-major col within proj
        int o    = ((pcol & 15) << 3) | (pcol >> 4);
        wrow[cf] = (seg * 128 + o) * 128;
        jseg[cf] = seg;
        pcb[cf]  = pcol;
    }

    #pragma unroll
    for (int t = 0; t < 4; ++t) {
        int k0   = t * 32 + kg * 8;
        int slot = t * 4 + kg;
        bf16x8 bh[3];
        #pragma unroll
        for (int cf = 0; cf < 3; ++cf)
            bh[cf] = *(const bf16x8*)&Whi[wrow[cf] + k0];
        bf16x8 ah[4];
        #pragma unroll
        for (int rf = 0; rf < 4; ++rf) {
            int row = rf * 16 + r;
            int s2  = slot ^ (r & 7);
            ah[rf] = *(bf16x8*)&As[row * 128 + s2 * 8];
        }
        #pragma unroll
        for (int cf = 0; cf < 3; ++cf)
            #pragma unroll
            for (int rf = 0; rf < 4; ++rf)
                acc[cf][rf] = __builtin_amdgcn_mfma_f32_16x16x32_bf16(ah[rf], bh[cf], acc[cf][rf], 0, 0, 0);
    }

    // ---- epilogue: q direct bf16; kv via LDS (full 16B groups) ----
    __syncthreads();
    __bf16* kvs = &As[0];                   // 64 x 128 bf16 = 16 KB
    int orow = kg * 4;
    #pragma unroll
    for (int cf = 0; cf < 3; ++cf) {
        int j    = jseg[cf];
        int pcol = pcb[cf];
        float b  = bias384[j * 128 + pcol];
        #pragma unroll
        for (int rf = 0; rf < 4; ++rf) {
            #pragma unroll
            for (int e = 0; e < 4; ++e) {
                int mrow = rf * 16 + orow + e;      // 0..63
                float val = acc[cf][rf][e] + b;
                if (j == 0) {
                    int mg = m0 + mrow;
                    if (mg < M) q[(size_t)mg * 128 + pcol] = (__bf16)val;
                } else {
                    int gl  = (pcol & 63) >> 2;     // local group 0..15
                    int idx = gl * 8 + ((j == 1) ? 0 : 4) + (pcol & 3);
                    kvs[mrow * 128 + idx] = (__bf16)val;
                }
            }
        }
    }
    __syncthreads();
    #pragma unroll
    for (int it = 0; it < 4; ++it) {
        int flat = it * 256 + tid;          // 16B chunk 0..1023
        int row  = flat >> 4;               // 0..63
        int u    = flat & 15;               // group within half
        int mg   = m0 + row;
        if (mg < M)
            *(uint4*)&kv[(size_t)mg * 256 + by * 128 + u * 8] =
                *(uint4*)&kvs[row * 128 + u * 8];
    }
}

// ---------------------------------------------------------------------------
// Kernel 3: fused SDDMM + online segment-softmax + SPMM.
// Main loop: 8 valid edges per wave-iter (4 per 32-lane half), pairwise
// softmax tree merged into running state once per iter (shorter dep chain,
// 4 gathers in flight).  Output: single bf16 ob (head-major, coalesced).
// ---------------------------------------------------------------------------
__device__ __forceinline__ float blo(unsigned u) { return __uint_as_float(u << 16); }
__device__ __forceinline__ float bhi(unsigned u) { return __uint_as_float(u & 0xffff0000u); }

__global__ __launch_bounds__(256)
void edge_attn_kernel(const int* __restrict__ row_ptr, const int* __restrict__ col,
                      const __bf16* __restrict__ q, const __bf16* __restrict__ kv,
                      __bf16* __restrict__ ob, int N_) {
    int wave = threadIdx.x >> 6;
    int lane = threadIdx.x & 63;
    int node = blockIdx.x * 4 + wave;
    if (node >= N_) return;
    int sl   = lane & 31;
    int half = lane >> 5;

    uint2 qu = *(const uint2*)&q[(size_t)node * 128 + sl * 4];
    float qx = blo(qu.x), qy = bhi(qu.x), qz = blo(qu.y), qw = bhi(qu.y);

    int e0 = row_ptr[node];
    int e1 = row_ptr[node + 1];

    float m = -INFINITY, z = 0.f;
    float4 acc = make_float4(0.f, 0.f, 0.f, 0.f);

    auto score = [&](uint4 u) {
        float p = qx * blo(u.x) + qy * bhi(u.x) +
                  qz * blo(u.y) + qw * bhi(u.y);
        p += __shfl_xor(p, 1);
        p += __shfl_xor(p, 2);
        return p * 0.25f;                       // 1/sqrt(DH)
    };

    int eb = e0;
    // main loop: 8 valid edges per iter (4 per half), no masking
    for (; eb + 8 <= e1; eb += 8) {
        int ea = eb + half * 4;
        int c0 = col[ea], c1 = col[ea + 1], c2 = col[ea + 2], c3 = col[ea + 3];
        uint4 u0 = *(const uint4*)(kv + (size_t)c0 * 256 + sl * 8);
        uint4 u1 = *(const uint4*)(kv + (size_t)c1 * 256 + sl * 8);
        uint4 u2 = *(const uint4*)(kv + (size_t)c2 * 256 + sl * 8);
        uint4 u3 = *(const uint4*)(kv + (size_t)c3 * 256 + sl * 8);
        float s0 = score(u0), s1 = score(u1), s2 = score(u2), s3 = score(u3);
        float m03 = fmaxf(fmaxf(s0, s1), fmaxf(s2, s3));
        float w0 = __expf(s0 - m03), w1 = __expf(s1 - m03);
        float w2 = __expf(s2 - m03), w3 = __expf(s3 - m03);
        float zl = (w0 + w1) + (w2 + w3);
        float lx = w0 * blo(u0.z) + w1 * blo(u1.z) + w2 * blo(u2.z) + w3 * blo(u3.z);
        float ly = w0 * bhi(u0.z) + w1 * bhi(u1.z) + w2 * bhi(u2.z) + w3 * bhi(u3.z);
        float lz = w0 * blo(u0.w) + w1 * blo(u1.w) + w2 * blo(u2.w) + w3 * blo(u3.w);
        float lw = w0 * bhi(u0.w) + w1 * bhi(u1.w) + w2 * bhi(u2.w) + w3 * bhi(u3.w);
        float mn = fmaxf(m, m03);
        float a1 = __expf(m - mn);              // m=-inf -> 0
        float a2 = __expf(m03 - mn);
        z = z * a1 + zl * a2;
        acc.x = acc.x * a1 + lx * a2;
        acc.y = acc.y * a1 + ly * a2;
        acc.z = acc.z * a1 + lz * a2;
        acc.w = acc.w * a1 + lw * a2;
        m = mn;
    }
    // tail: up to 7 edges, masked, 2 per iter across halves
    for (; eb < e1; eb += 2) {
        int my_e   = eb + half;
        bool valid = (my_e < e1);
        int cnode  = valid ? col[my_e] : col[eb];
        uint4 u = *(const uint4*)(kv + (size_t)cnode * 256 + sl * 8);
        float s = valid ? score(u) : -INFINITY;
        float mnew = fmaxf(m, s);
        if (mnew > -INFINITY) {
            float alpha = __expf(m - mnew);
            float w     = __expf(s - mnew);
            z = z * alpha + w;
            acc.x = acc.x * alpha + w * blo(u.z);
            acc.y = acc.y * alpha + w * bhi(u.z);
            acc.z = acc.z * alpha + w * blo(u.w);
            acc.w = acc.w * alpha + w * bhi(u.w);
            m = mnew;
        }
    }

    // merge the two halves (lane pairs with lane^32, same sl)
    float m2 = __shfl_xor(m, 32);
    float z2 = __shfl_xor(z, 32);
    float ax = __shfl_xor(acc.x, 32);
    float ay = __shfl_xor(acc.y, 32);
    float az = __shfl_xor(acc.z, 32);
    float aw = __shfl_xor(acc.w, 32);
    float mm = fmaxf(m, m2);
    if (mm > -INFINITY) {
        float a1 = __expf(m - mm);
        float a2 = __expf(m2 - mm);
        z = z * a1 + z2 * a2;
        acc.x = acc.x * a1 + ax * a2;
        acc.y = acc.y * a1 + ay * a2;
        acc.z = acc.z * a1 + az * a2;
        acc.w = acc.w * a1 + aw * a2;
    }

    if (half == 0) {
        float inv = (z > 0.f) ? 1.0f / z : 0.f;
        bf16x4 hv4;
        hv4[0] = (__bf16)(acc.x * inv);
        hv4[1] = (__bf16)(acc.y * inv);
        hv4[2] = (__bf16)(acc.z * inv);
        hv4[3] = (__bf16)(acc.w * inv);
        *(bf16x4*)&ob[(size_t)node * 128 + sl * 4] = hv4;   // head-major
    }
}

// ---------------------------------------------------------------------------
// Kernel 4: output projection, single-term bf16 MFMA.  A = ob bf16
// head-major; Wo K-permuted at prep.  Grid (M/64, 2); 4 waves x 16 cols.
// Per k-step: 1 W load, 4 ds_read_b128, 4 MFMA.  16 KB LDS.
// ---------------------------------------------------------------------------
__global__ __launch_bounds__(256)
void outproj_mfma_kernel(const __bf16* __restrict__ A_g, int M,
                         const __bf16* __restrict__ Whi,
                         const float* __restrict__ bo, float* __restrict__ C) {
    __shared__ __bf16 As[64 * 128];
    int tid  = threadIdx.x;
    int wv   = tid >> 6;
    int lane = tid & 63;
    int r    = lane & 15;
    int kg   = lane >> 4;
    int m0   = blockIdx.x * 64;
    int by   = blockIdx.y;
    int col  = by * 64 + wv * 16 + r;       // output column (natural)

    #pragma unroll
    for (int it = 0; it < 4; ++it) {
        int flat = it * 256 + tid;
        int row  = flat >> 4;
        int s    = flat & 15;
        int g    = s ^ (row & 7);
        int grow = m0 + row; if (grow > M - 1) grow = M - 1;
        *(bf16x8*)&As[row * 128 + s * 8] = *(const bf16x8*)&A_g[(size_t)grow * 128 + g * 8];
    }
    __syncthreads();

    f32x4 acc[4];
    #pragma unroll
    for (int rf = 0; rf < 4; ++rf) acc[rf] = (f32x4){0.f, 0.f, 0.f, 0.f};

    int wrow = col * 128;
    #pragma unroll
    for (int t = 0; t < 4; ++t) {
        int k0   = t * 32 + kg * 8;
        int slot = t * 4 + kg;
        bf16x8 bh = *(const bf16x8*)&Whi[wrow + k0];
        bf16x8 ah[4];
        #pragma unroll
        for (int rf = 0; rf < 4; ++rf) {
            int row = rf * 16 + r;
            int s2  = slot ^ (r & 7);
            ah[rf] = *(bf16x8*)&As[row * 128 + s2 * 8];
        }
        #pragma unroll
        for (int rf = 0; rf < 4; ++rf)
            acc[rf] = __builtin_amdgcn_mfma_f32_16x16x32_bf16(ah[rf], bh, acc[rf], 0, 0, 0);
    }

    float b = bo[col];
    #pragma unroll
    for (int rf = 0; rf < 4; ++rf) {
        #pragma unroll
        for (int e = 0; e < 4; ++e) {
            int mg = m0 + rf * 16 + kg * 4 + e;
            if (mg < M) C[(size_t)mg * 128 + col] = acc[rf][e] + b;
        }
    }
}

// ---------------------------------------------------------------------------
extern "C" void kernel_launch(void* const* d_in, const int* in_sizes, int n_in,
                              void* d_out, int out_size, void* d_ws, size_t ws_size,
                              hipStream_t stream) {
    const float* h  = (const float*)d_in[0];
    const int* row  = (const int*)d_in[1];
    const int* col  = (const int*)d_in[2];
    const float* Wq = (const float*)d_in[3];
    const float* bq = (const float*)d_in[4];
    const float* Wk = (const float*)d_in[5];
    const float* bk = (const float*)d_in[6];
    const float* Wv = (const float*)d_in[7];
    const float* bv = (const float*)d_in[8];
    const float* Wo = (const float*)d_in[9];
    const float* bo = (const float*)d_in[10];
    float* out = (float*)d_out;

    int N_ = in_sizes[0] / HID;   // 50000
    int E_ = in_sizes[1];         // 800000

    char* ws = (char*)d_ws;
    size_t off = 0;
    auto alloc = [&](size_t bytes) {
        void* p = (void*)(ws + off);
        off = (off + bytes + 255) & ~(size_t)255;
        return p;
    };
    int*    row_ptr = (int*)   alloc((size_t)(N_ + 1) * sizeof(int));
    __bf16* qb      = (__bf16*)alloc((size_t)N_ * 128 * sizeof(__bf16));
    __bf16* kvb     = (__bf16*)alloc((size_t)N_ * 256 * sizeof(__bf16));
    __bf16* obb     = (__bf16*)alloc((size_t)N_ * 128 * sizeof(__bf16));
    __bf16* Whi     = (__bf16*)alloc((size_t)4 * 16384 * sizeof(__bf16));
    float*  bias384 = (float*) alloc(384 * sizeof(float));
    (void)ws_size;

    prep_kernel<<<256, 256, 0, stream>>>(row, row_ptr, N_, E_,
                                         Wq, Wk, Wv, Wo, bq, bk, bv,
                                         Whi, bias384);
    qkv_mfma_kernel<<<dim3((N_ + 63) / 64, 2), 256, 0, stream>>>(
        h, N_, Whi, bias384, qb, kvb);
    edge_attn_kernel<<<(N_ + 3) / 4, 256, 0, stream>>>(row_ptr, col, qb, kvb, obb, N_);
    outproj_mfma_kernel<<<dim3((N_ + 63) / 64, 2), 256, 0, stream>>>(
        obb, N_, Whi + 3 * 16384, bo, out);
}